// Round 15
// baseline (341.505 us; speedup 1.0000x reference)
//
#include <hip/hip_runtime.h>

// RelativePositionalMask: out[h][j][i] = bias[ sidx(i,j) + tidx(i,j)*32 ][h]
// Output 302 MB fp32 -> write-BW bound (~48us @6.3TB/s). Reported dur_us
// includes a ~195us harness poison fill; kernel residual ~110us.
//
// R10-R14: nt/unroll/launch-bounds/gather-source/h-order all neutral.
// Remaining structural delta vs the 78%-of-peak fill kernels: per-wave store
// stream granularity (1KB bursts hopping between 8-32 streams) and
// compute/gather latency coupled into the store loop.
//
// R15: two-kernel pipeline.
//  K1: all 9.4M indices (bit-exact math unchanged) -> u16 ws[j][i] (18.9MB).
//  K2: task=(h,j) row; block streams 24 rows = 288KB contiguous (fill-like),
//      idx loads coalesced (L3-hot after plane 0), bias gathered from
//      [h][row] LDS (DS pipe, overlapped).
// Fallback to the proven R12 fused kernel if ws_size < 18.9MB.

typedef float v4f __attribute__((ext_vector_type(4)));
typedef unsigned short u16;
typedef u16 v4u16 __attribute__((ext_vector_type(4)));

constexpr int N     = 3072;
constexpr int NHEAD = 8;
constexpr int NSP   = 32;
constexpr int NTB   = 33;
constexpr int NROW  = NTB * NSP;   // 1056

// ---------------- kernel 1: idx precompute (bit-exact math) ----------------
__global__ __launch_bounds__(256) void idx_kernel(
    const float* __restrict__ coords,   // (N,3): frame, x, y
    const float* __restrict__ sbins,    // (NSP)
    u16* __restrict__ idxws)            // (N,N): [j][i] = idx(i,j)
{
#pragma clang fp contract(off)
    const int i0 = (blockIdx.x * 256 + threadIdx.x) * 4;
    const int j0 = blockIdx.y * 4;

    float sb[NSP];
#pragma unroll
    for (int k = 0; k < NSP; ++k) sb[k] = sbins[k];

    const v4f c0 = *(const v4f*)(coords + (size_t)i0 * 3 + 0);
    const v4f c1 = *(const v4f*)(coords + (size_t)i0 * 3 + 4);
    const v4f c2 = *(const v4f*)(coords + (size_t)i0 * 3 + 8);
    const float fi_[4] = {c0.x, c0.w, c1.z, c2.y};
    const float px_[4] = {c0.y, c1.x, c1.w, c2.z};
    const float py_[4] = {c0.z, c1.y, c2.x, c2.w};
    int ifr_[4];
#pragma unroll
    for (int k = 0; k < 4; ++k) ifr_[k] = (int)fi_[k];

#pragma unroll
    for (int jj = 0; jj < 4; ++jj) {
        const int j = j0 + jj;
        const float fj = coords[j * 3 + 0];
        const float qx = coords[j * 3 + 1];
        const float qy = coords[j * 3 + 2];
        const int jfr = (int)fj;
        v4u16 r;
#pragma unroll
        for (int k = 0; k < 4; ++k) {
            // exact reference float semantics (contract off, separate squares)
            const float dx  = px_[k] - qx;
            const float dy  = py_[k] - qy;
            const float dx2 = dx * dx;
            const float dy2 = dy * dy;
            const float d   = sqrtf(dx2 + dy2);
            int sc = 0;
#pragma unroll
            for (int b = 0; b < NSP; ++b) sc += (sb[b] < d) ? 1 : 0;
            if (sc > NSP - 1) sc = NSP - 1;
            int t = (ifr_[k] - jfr + 33) >> 1;
            t = t < 0 ? 0 : (t > NTB - 1 ? NTB - 1 : t);
            r[k] = (u16)(sc + t * NSP);
        }
        *(v4u16*)(idxws + (size_t)j * N + i0) = r;   // coalesced 8B/lane
    }
}

// ---------------- kernel 2: fill-like streaming writer ----------------
constexpr int BLOCKS2 = 1024;
constexpr int TASKS_PER_BLOCK = NHEAD * N / BLOCKS2;   // 24 rows = 288KB/block

__global__ __launch_bounds__(256, 4) void write_kernel(
    const float* __restrict__ bias,     // (NROW, NHEAD)
    const u16* __restrict__ idxws,      // (N,N) [j][i]
    float* __restrict__ out)            // (NHEAD, N, N)
{
    __shared__ float lds_bh[NHEAD * NROW];   // transposed [h][row], 33.8KB
    for (int e = threadIdx.x; e < NROW * NHEAD; e += 256)
        lds_bh[(e & 7) * NROW + (e >> 3)] = bias[e];   // coalesced read
    __syncthreads();

    const int t = threadIdx.x;
    const int task0 = blockIdx.x * TASKS_PER_BLOCK;
#pragma unroll 1
    for (int s = 0; s < TASKS_PER_BLOCK; ++s) {
        const int task = task0 + s;
        const int h = task / N;
        const int j = task - h * N;
        const float* const lb = lds_bh + h * NROW;
        const u16* const iw = idxws + (size_t)j * N;
        float* const o = out + (size_t)h * N * N + (size_t)j * N;
#pragma unroll
        for (int k = 0; k < 3; ++k) {
            const int i0 = k * 1024 + t * 4;               // block covers row
            const v4u16 r = *(const v4u16*)(iw + i0);      // 512B/wave, L3-hot
            const v4f v = { lb[r.x], lb[r.y], lb[r.z], lb[r.w] };
            *(v4f*)(o + i0) = v;                           // 1KB/wave contig
        }
    }
}

// ---------------- fallback: proven R12 fused kernel (303.9us) ----------------
__global__ __launch_bounds__(256, 4) void rpm_fused(
    const float* __restrict__ coords, const float* __restrict__ bias,
    const float* __restrict__ sbins, float* __restrict__ out)
{
#pragma clang fp contract(off)
    __shared__ float lds_bias[NROW * NHEAD];
    {
        const v4f* gb = (const v4f*)bias;
        v4f* lb = (v4f*)lds_bias;
        for (int t = threadIdx.x; t < NROW * NHEAD / 4; t += 256) lb[t] = gb[t];
    }
    const int i0 = (blockIdx.x * 256 + threadIdx.x) * 4;
    const int j0 = blockIdx.y * 4;
    float sb[NSP];
#pragma unroll
    for (int k = 0; k < NSP; ++k) sb[k] = sbins[k];
    const v4f c0 = *(const v4f*)(coords + (size_t)i0 * 3 + 0);
    const v4f c1 = *(const v4f*)(coords + (size_t)i0 * 3 + 4);
    const v4f c2 = *(const v4f*)(coords + (size_t)i0 * 3 + 8);
    const float fi_[4] = {c0.x, c0.w, c1.z, c2.y};
    const float px_[4] = {c0.y, c1.x, c1.w, c2.z};
    const float py_[4] = {c0.z, c1.y, c2.x, c2.w};
    int ifr_[4];
#pragma unroll
    for (int k = 0; k < 4; ++k) ifr_[k] = (int)fi_[k];
    const size_t hs = (size_t)N * N;
    float* const outb = out + i0;
    __syncthreads();
#pragma unroll 2
    for (int jj = 0; jj < 4; ++jj) {
        const int j = j0 + jj;
        const float fj = coords[j * 3 + 0];
        const float qx = coords[j * 3 + 1];
        const float qy = coords[j * 3 + 2];
        const int jfr = (int)fj;
        v4f b0_[4], b1_[4];
#pragma unroll
        for (int k = 0; k < 4; ++k) {
            const float dx  = px_[k] - qx;
            const float dy  = py_[k] - qy;
            const float dx2 = dx * dx;
            const float dy2 = dy * dy;
            const float d   = sqrtf(dx2 + dy2);
            int sc = 0;
#pragma unroll
            for (int b = 0; b < NSP; ++b) sc += (sb[b] < d) ? 1 : 0;
            if (sc > NSP - 1) sc = NSP - 1;
            int t = (ifr_[k] - jfr + 33) >> 1;
            t = t < 0 ? 0 : (t > NTB - 1 ? NTB - 1 : t);
            const v4f* bp = (const v4f*)(lds_bias + (size_t)(sc + t * NSP) * NHEAD);
            b0_[k] = bp[0];
            b1_[k] = bp[1];
        }
        float* const o = outb + (size_t)j * N;
        const v4f v0 = {b0_[0].x, b0_[1].x, b0_[2].x, b0_[3].x};
        const v4f v1 = {b0_[0].y, b0_[1].y, b0_[2].y, b0_[3].y};
        const v4f v2 = {b0_[0].z, b0_[1].z, b0_[2].z, b0_[3].z};
        const v4f v3 = {b0_[0].w, b0_[1].w, b0_[2].w, b0_[3].w};
        const v4f v4 = {b1_[0].x, b1_[1].x, b1_[2].x, b1_[3].x};
        const v4f v5 = {b1_[0].y, b1_[1].y, b1_[2].y, b1_[3].y};
        const v4f v6 = {b1_[0].z, b1_[1].z, b1_[2].z, b1_[3].z};
        const v4f v7 = {b1_[0].w, b1_[1].w, b1_[2].w, b1_[3].w};
        *(v4f*)(o + 0 * hs) = v0;  *(v4f*)(o + 1 * hs) = v1;
        *(v4f*)(o + 2 * hs) = v2;  *(v4f*)(o + 3 * hs) = v3;
        *(v4f*)(o + 4 * hs) = v4;  *(v4f*)(o + 5 * hs) = v5;
        *(v4f*)(o + 6 * hs) = v6;  *(v4f*)(o + 7 * hs) = v7;
    }
}

extern "C" void kernel_launch(void* const* d_in, const int* in_sizes, int n_in,
                              void* d_out, int out_size, void* d_ws, size_t ws_size,
                              hipStream_t stream) {
    const float* coords = (const float*)d_in[0];
    const float* bias   = (const float*)d_in[1];
    const float* sbins  = (const float*)d_in[2];
    float* out = (float*)d_out;

    const size_t need = (size_t)N * N * sizeof(u16);   // 18.9 MB
    if (ws_size >= need) {
        u16* idxws = (u16*)d_ws;
        idx_kernel<<<dim3(N / 1024, N / 4), dim3(256), 0, stream>>>(coords, sbins, idxws);
        write_kernel<<<dim3(BLOCKS2), dim3(256), 0, stream>>>(bias, idxws, out);
    } else {
        rpm_fused<<<dim3(N / 1024, N / 4), dim3(256), 0, stream>>>(coords, bias, sbins, out);
    }
}